// Round 3
// baseline (867.824 us; speedup 1.0000x reference)
//
#include <hip/hip_runtime.h>
#include <hip/hip_fp16.h>

#define BATCH 32
#define H 1024
#define W 1024
#define NPIX (H * W)       // 1048576 per sample
#define ITERS 10
#define SROWS 8            // rows per 128-thread sub-group
#define BROWS 16           // rows per block (2 sub-groups)
#define STRIPS (H / BROWS)            // 64 strips per image
#define TOTAL_STRIPS (BATCH * STRIPS) // 2048 blocks -> 8 blocks/CU on 256 CUs

typedef _Float16 half8_t __attribute__((ext_vector_type(8)));

// Per-(iteration, batch) reduction state.
struct Stats {
    unsigned maxbits[ITERS][BATCH];  // fp32 bits; all values >= 0 so uint order == float order
    unsigned minbits[ITERS][BATCH];
    double   sum[ITERS][BATCH];
};

__global__ void init_stats(Stats* st) {
    int i = blockIdx.x * blockDim.x + threadIdx.x;
    if (i < ITERS * BATCH) {
        (&st->maxbits[0][0])[i] = 0u;           // erosion >= 0 everywhere
        (&st->minbits[0][0])[i] = 0x7f800000u;  // +inf
        (&st->sum[0][0])[i]     = 0.0;
    }
}

__device__ __forceinline__ float bsq(float p, int t) {
    float d = p - (t == 0 ? 1.f : 0.f);
    return d * d;
}

// Raw (unconverted) row staging. Loads land here with no dependent ALU at
// issue time; conversion happens one loop iteration later -> each load gets
// a full iteration of compute as latency cover.
template <int MODE> struct Raw;
template <> struct Raw<0> { float4 p0, p1; int4 t0, t1; float pL, pR; int tL, tR; };
template <> struct Raw<1> { half8_t x; _Float16 xL, xR; };

template <int MODE>
__device__ __forceinline__ void issue_row(const float* __restrict__ pred,
    const int* __restrict__ target, const _Float16* __restrict__ in,
    size_t base, int r, int lane128, Raw<MODE>& raw)
{
    const bool inb = (r >= 0) && (r < H);
    if (!inb) return;                       // OOB: raw never read by convert
    const int wl = lane128 & 63;
    const size_t off = base + (size_t)r * W + (size_t)(lane128 * 8);
    if constexpr (MODE == 0) {
        raw.p0 = *(const float4*)(pred + off);
        raw.p1 = *(const float4*)(pred + off + 4);
        raw.t0 = *(const int4*)(target + off);
        raw.t1 = *(const int4*)(target + off + 4);
        // cross-wave neighbor scalars (2 lanes per wave)
        if (wl == 0 && lane128 != 0)    { raw.pL = pred[off - 1]; raw.tL = target[off - 1]; }
        if (wl == 63 && lane128 != 127) { raw.pR = pred[off + 8]; raw.tR = target[off + 8]; }
    } else {
        raw.x = *(const half8_t*)(in + off);
        if (wl == 0 && lane128 != 0)    raw.xL = in[off - 1];
        if (wl == 63 && lane128 != 127) raw.xR = in[off + 8];
    }
}

// Materialize row r as fp32 f[0..8) (normalized for MODE 1) plus its
// cross-wave edge scalars (valid only for lanes wl==0/63; others never read
// them). Pure ALU on staged registers -- no memory waits here.
template <int MODE>
__device__ __forceinline__ void convert_row(int r, int lane128,
    float emin, float invd, const Raw<MODE>& raw,
    float f[8], float& eL, float& eR)
{
    const bool inb = (r >= 0) && (r < H);
    const int wl = lane128 & 63;
    if (!inb) {
        #pragma unroll
        for (int j = 0; j < 8; ++j) f[j] = 0.f;
        eL = 0.f; eR = 0.f;
        return;
    }
    if constexpr (MODE == 0) {
        f[0] = bsq(raw.p0.x, raw.t0.x); f[1] = bsq(raw.p0.y, raw.t0.y);
        f[2] = bsq(raw.p0.z, raw.t0.z); f[3] = bsq(raw.p0.w, raw.t0.w);
        f[4] = bsq(raw.p1.x, raw.t1.x); f[5] = bsq(raw.p1.y, raw.t1.y);
        f[6] = bsq(raw.p1.z, raw.t1.z); f[7] = bsq(raw.p1.w, raw.t1.w);
        eL = (wl == 0 && lane128 != 0)    ? bsq(raw.pL, raw.tL) : 0.f;
        eR = (wl == 63 && lane128 != 127) ? bsq(raw.pR, raw.tR) : 0.f;
    } else {
        #pragma unroll
        for (int j = 0; j < 8; ++j) f[j] = ((float)raw.x[j] - emin) * invd;
        eL = (wl == 0 && lane128 != 0)    ? ((float)raw.xL - emin) * invd : 0.f;
        eR = (wl == 63 && lane128 != 127) ? ((float)raw.xR - emin) * invd : 0.f;
    }
}

// One strip = 16 rows of one image; threads 0-127 rows [r0,r0+8),
// threads 128-255 rows [r0+8,r0+16); 8 px/thread. 3-row fp32 sliding window
// with double-buffered raw lookahead: while computing row r, row r+2's load
// is in flight and row r+1 (issued last iteration) is converted.
template <int MODE, int STORE>
__device__ __forceinline__ void do_strip(
    const float* __restrict__ pred, const int* __restrict__ target,
    const _Float16* __restrict__ in, _Float16* __restrict__ out,
    Stats* __restrict__ st, int iter, int strip, int tid)
{
    const int b   = strip >> 6;            // / STRIPS (=64)
    const int s   = strip & (STRIPS - 1);
    const int sub     = tid >> 7;          // 0 or 1
    const int lane128 = tid & 127;
    const int wl      = lane128 & 63;
    const int r0  = s * BROWS + sub * SROWS;
    const int col = lane128 * 8;
    const size_t base = (size_t)b * NPIX;

    float emin = 0.f, invd = 1.f;
    if (MODE == 1) {
        float emax  = __uint_as_float(st->maxbits[iter - 1][b]);
        float emn   = __uint_as_float(st->minbits[iter - 1][b]);
        float denom = emax - emn;
        if (denom != 0.f) { emin = emn; invd = 1.f / denom; }
        // else: identity -> erosion kept raw, matching reference
    }

    Raw<MODE> rA, rB;
    float prev[8], cur[8], nxt[8];
    float eLc, eRc, eLn, eRn, dL, dR;

    // Prologue: rows r0-1 (prev) and r0 (cur); then issue r0+1 into rA.
    issue_row<MODE>(pred, target, in, base, r0 - 1, lane128, rA);
    issue_row<MODE>(pred, target, in, base, r0,     lane128, rB);
    convert_row<MODE>(r0 - 1, lane128, emin, invd, rA, prev, dL, dR);
    convert_row<MODE>(r0,     lane128, emin, invd, rB, cur, eLc, eRc);
    issue_row<MODE>(pred, target, in, base, r0 + 1, lane128, rA);

    float  m  = 0.f;                 // erosion >= 0
    float  mn = __builtin_inf();
    double sum = 0.0;

    #pragma unroll
    for (int i = 0; i < SROWS; ++i) {
        const int r = r0 + i;
        // stage row r+2 (skipped on last iteration: exactly 10 rows loaded)
        if (i < SROWS - 1) {
            if (i & 1) issue_row<MODE>(pred, target, in, base, r + 2, lane128, rA);
            else       issue_row<MODE>(pred, target, in, base, r + 2, lane128, rB);
        }
        // convert row r+1 (its load was issued one iteration ago)
        if (i & 1) convert_row<MODE>(r + 1, lane128, emin, invd, rB, nxt, eLn, eRn);
        else       convert_row<MODE>(r + 1, lane128, emin, invd, rA, nxt, eLn, eRn);

        // horizontal neighbors of cur (converted >=1 iteration ago -> no wait)
        float L = __shfl_up(cur[7], 1, 64);
        float R = __shfl_down(cur[0], 1, 64);
        if (lane128 == 0)   L = 0.f;       // image left edge
        else if (wl == 0)   L = eLc;       // cross-wave
        if (lane128 == 127) R = 0.f;       // image right edge
        else if (wl == 63)  R = eRc;       // cross-wave

        // dilation = 0.2*(c + l + r + up + dn); erosion = relu(d - 0.5)
        float e[8];
        #pragma unroll
        for (int j = 0; j < 8; ++j) {
            float lf = (j == 0) ? L : cur[j - 1];
            float rf = (j == 7) ? R : cur[j + 1];
            e[j] = fmaxf(0.2f * (cur[j] + lf + rf + prev[j] + nxt[j]) - 0.5f, 0.f);
        }

        if (STORE) {
            half8_t o;
            #pragma unroll
            for (int j = 0; j < 8; ++j) o[j] = (_Float16)e[j];
            *(half8_t*)(out + base + (size_t)r * W + col) = o;
        }

        float rm = fmaxf(fmaxf(fmaxf(e[0], e[1]), fmaxf(e[2], e[3])),
                         fmaxf(fmaxf(e[4], e[5]), fmaxf(e[6], e[7])));
        float rn = fminf(fminf(fminf(e[0], e[1]), fminf(e[2], e[3])),
                         fminf(fminf(e[4], e[5]), fminf(e[6], e[7])));
        float rs = ((e[0] + e[1]) + (e[2] + e[3])) + ((e[4] + e[5]) + (e[6] + e[7]));
        m   = fmaxf(m, rm);
        mn  = fminf(mn, rn);
        sum += (double)rs;

        #pragma unroll
        for (int j = 0; j < 8; ++j) { prev[j] = cur[j]; cur[j] = nxt[j]; }
        eLc = eLn; eRc = eRn;
    }

    // Block reduction: max / min / sum(double), then one atomic set per block.
    #pragma unroll
    for (int off = 32; off > 0; off >>= 1) {
        m   = fmaxf(m,  __shfl_down(m,  off, 64));
        mn  = fminf(mn, __shfl_down(mn, off, 64));
        sum += __shfl_down(sum, off, 64);
    }
    __shared__ float  smax[4];
    __shared__ float  smin[4];
    __shared__ double ssum[4];
    const int lane = tid & 63, wave = tid >> 6;
    if (lane == 0) { smax[wave] = m; smin[wave] = mn; ssum[wave] = sum; }
    __syncthreads();
    if (tid == 0) {
        m   = fmaxf(fmaxf(smax[0], smax[1]), fmaxf(smax[2], smax[3]));
        mn  = fminf(fminf(smin[0], smin[1]), fminf(smin[2], smin[3]));
        sum = ssum[0] + ssum[1] + ssum[2] + ssum[3];
        atomicMax(&st->maxbits[iter][b], __float_as_uint(m));
        atomicMin(&st->minbits[iter][b], __float_as_uint(mn));
        atomicAdd(&st->sum[iter][b], sum);
    }
}

// Iteration 0: reads pred(fp32)+target(int32), 256 MB compulsory -> HBM-bound
// once pipelined. Raw staging costs ~40 VGPR; allow 6 waves/EU (<=85 VGPR).
__global__ __launch_bounds__(256, 6) void erode0(
    const float* __restrict__ pred, const int* __restrict__ target,
    _Float16* __restrict__ out, Stats* __restrict__ st)
{
    do_strip<0, 1>(pred, target, nullptr, out, st, 0, blockIdx.x, threadIdx.x);
}

// Iterations 1..9: fp16 field (64 MB, L3-resident). Light registers -> 8
// blocks/CU (100% occupancy cap).
template <int STORE>
__global__ __launch_bounds__(256, 8) void erode1(
    const _Float16* __restrict__ in, _Float16* __restrict__ out,
    Stats* __restrict__ st, int iter)
{
    do_strip<1, STORE>(nullptr, nullptr, in, out, st, iter, blockIdx.x, threadIdx.x);
}

// loss = (1/(B*N)) * sum_k (k+1)^2 * [ (sum_raw - N*emin)/denom  if denom != 0 else sum_raw ]
__global__ void finalize(const Stats* __restrict__ st, float* __restrict__ out) {
    if (threadIdx.x == 0 && blockIdx.x == 0) {
        double total = 0.0;
        for (int k = 0; k < ITERS; ++k) {
            double w = (double)((k + 1) * (k + 1));
            for (int b = 0; b < BATCH; ++b) {
                float emax  = __uint_as_float(st->maxbits[k][b]);
                float emn   = __uint_as_float(st->minbits[k][b]);
                float denom = emax - emn;
                double s = st->sum[k][b];
                double sn;
                if (denom != 0.f)
                    sn = (s - (double)NPIX * (double)emn) / (double)denom;
                else
                    sn = s;
                total += w * sn;
            }
        }
        out[0] = (float)(total / ((double)BATCH * (double)NPIX));
    }
}

extern "C" void kernel_launch(void* const* d_in, const int* in_sizes, int n_in,
                              void* d_out, int out_size, void* d_ws, size_t ws_size,
                              hipStream_t stream) {
    (void)in_sizes; (void)n_in; (void)out_size;
    const float* pred   = (const float*)d_in[0];
    const int*   target = (const int*)d_in[1];

    const size_t fieldBytes = (size_t)BATCH * NPIX * sizeof(_Float16);  // 64 MB
    char* ws = (char*)d_ws;
    _Float16* bufA;
    _Float16* bufB;
    Stats* st;
    if (ws_size >= 2 * fieldBytes + sizeof(Stats)) {
        bufA = (_Float16*)ws;
        bufB = (_Float16*)(ws + fieldBytes);
        st   = (Stats*)(ws + 2 * fieldBytes);
    } else {
        // target is dead after iteration 0 (128 MB int32 holds the 64 MB fp16
        // field); harness restores d_in before every launch. k=0 reads target
        // and writes bufA; bufB (=target memory) is first written at k=1.
        bufA = (_Float16*)ws;
        bufB = (_Float16*)d_in[1];
        st   = (Stats*)(ws + fieldBytes);
    }

    init_stats<<<1, 320, 0, stream>>>(st);

    dim3 grid(TOTAL_STRIPS), block(256);
    erode0<<<grid, block, 0, stream>>>(pred, target, bufA, st);

    _Float16* src = bufA;
    _Float16* dst = bufB;
    for (int k = 1; k < ITERS; ++k) {
        if (k == ITERS - 1)
            erode1<0><<<grid, block, 0, stream>>>(src, nullptr, st, k);
        else
            erode1<1><<<grid, block, 0, stream>>>(src, dst, st, k);
        _Float16* t = src; src = dst; dst = t;
    }

    finalize<<<1, 64, 0, stream>>>(st, (float*)d_out);
}

// Round 4
// 604.907 us; speedup vs baseline: 1.4346x; 1.4346x over previous
//
#include <hip/hip_runtime.h>
#include <hip/hip_fp16.h>

#define BATCH 32
#define H 1024
#define W 1024
#define NPIX (H * W)       // 1048576 per sample
#define ITERS 10
#define SROWS 16           // rows per 128-thread sub-group
#define BROWS 32           // rows per block (2 sub-groups)
#define STRIPS (H / BROWS)            // 32 strips per image
#define TOTAL_STRIPS (BATCH * STRIPS) // 1024 blocks -> 4 blocks/CU on 256 CUs

typedef _Float16 half8_t __attribute__((ext_vector_type(8)));

// Per-(iteration, batch) reduction state.
struct Stats {
    unsigned maxbits[ITERS][BATCH];  // fp32 bits; all values >= 0 so uint order == float order
    unsigned minbits[ITERS][BATCH];
    double   sum[ITERS][BATCH];
};

__global__ void init_stats(Stats* st) {
    int i = blockIdx.x * blockDim.x + threadIdx.x;
    if (i < ITERS * BATCH) {
        (&st->maxbits[0][0])[i] = 0u;           // erosion >= 0 everywhere
        (&st->minbits[0][0])[i] = 0x7f800000u;  // +inf
        (&st->sum[0][0])[i]     = 0.0;
    }
}

__device__ __forceinline__ float bsq(float p, int t) {
    float d = p - (t == 0 ? 1.f : 0.f);
    return d * d;
}

// Raw (unconverted) row staging. Loads land here with no dependent ALU at
// issue time; conversion happens one loop iteration later -> each load gets
// a full iteration of compute as latency cover.
template <int MODE> struct Raw;
template <> struct Raw<0> { float4 p0, p1; int4 t0, t1; float pL, pR; int tL, tR; };
template <> struct Raw<1> { half8_t x; _Float16 xL, xR; };

template <int MODE>
__device__ __forceinline__ void issue_row(const float* __restrict__ pred,
    const int* __restrict__ target, const _Float16* __restrict__ in,
    size_t base, int r, int lane128, Raw<MODE>& raw)
{
    const bool inb = (r >= 0) && (r < H);
    if (!inb) return;                       // OOB: raw never read by convert
    const int wl = lane128 & 63;
    const size_t off = base + (size_t)r * W + (size_t)(lane128 * 8);
    if constexpr (MODE == 0) {
        raw.p0 = *(const float4*)(pred + off);
        raw.p1 = *(const float4*)(pred + off + 4);
        raw.t0 = *(const int4*)(target + off);
        raw.t1 = *(const int4*)(target + off + 4);
        // cross-wave neighbor scalars (2 lanes per wave)
        if (wl == 0 && lane128 != 0)    { raw.pL = pred[off - 1]; raw.tL = target[off - 1]; }
        if (wl == 63 && lane128 != 127) { raw.pR = pred[off + 8]; raw.tR = target[off + 8]; }
    } else {
        raw.x = *(const half8_t*)(in + off);
        if (wl == 0 && lane128 != 0)    raw.xL = in[off - 1];
        if (wl == 63 && lane128 != 127) raw.xR = in[off + 8];
    }
}

// Materialize row r as fp32 f[0..8) (normalized for MODE 1) plus its
// cross-wave edge scalars (valid only for lanes wl==0/63; others never read
// them). Pure ALU on staged registers -- no memory waits here.
template <int MODE>
__device__ __forceinline__ void convert_row(int r, int lane128,
    float emin, float invd, const Raw<MODE>& raw,
    float f[8], float& eL, float& eR)
{
    const bool inb = (r >= 0) && (r < H);
    const int wl = lane128 & 63;
    if (!inb) {
        #pragma unroll
        for (int j = 0; j < 8; ++j) f[j] = 0.f;
        eL = 0.f; eR = 0.f;
        return;
    }
    if constexpr (MODE == 0) {
        f[0] = bsq(raw.p0.x, raw.t0.x); f[1] = bsq(raw.p0.y, raw.t0.y);
        f[2] = bsq(raw.p0.z, raw.t0.z); f[3] = bsq(raw.p0.w, raw.t0.w);
        f[4] = bsq(raw.p1.x, raw.t1.x); f[5] = bsq(raw.p1.y, raw.t1.y);
        f[6] = bsq(raw.p1.z, raw.t1.z); f[7] = bsq(raw.p1.w, raw.t1.w);
        eL = (wl == 0 && lane128 != 0)    ? bsq(raw.pL, raw.tL) : 0.f;
        eR = (wl == 63 && lane128 != 127) ? bsq(raw.pR, raw.tR) : 0.f;
    } else {
        #pragma unroll
        for (int j = 0; j < 8; ++j) f[j] = ((float)raw.x[j] - emin) * invd;
        eL = (wl == 0 && lane128 != 0)    ? ((float)raw.xL - emin) * invd : 0.f;
        eR = (wl == 63 && lane128 != 127) ? ((float)raw.xR - emin) * invd : 0.f;
    }
}

// One loop step: stage row r+2 into `stage`, convert row r+1 from `conv`
// (issued one step ago), compute the stencil on the cur window, store, and
// accumulate stats. Window shifts at the end.
template <int MODE, int STORE>
__device__ __forceinline__ void strip_step(
    int i, int r0, int lane128, int wl, int col, size_t base,
    const float* __restrict__ pred, const int* __restrict__ target,
    const _Float16* __restrict__ in, _Float16* __restrict__ out,
    float emin, float invd,
    Raw<MODE>& stage, Raw<MODE>& conv,
    float prev[8], float cur[8], float nxt[8],
    float& eLc, float& eRc,
    float& m, float& mn, double& sum)
{
    const int r = r0 + i;
    // stage row r+2 (skipped on last step: exactly SROWS+2 rows loaded)
    if (i < SROWS - 1)
        issue_row<MODE>(pred, target, in, base, r + 2, lane128, stage);
    // convert row r+1 (its load was issued one step ago)
    float eLn, eRn;
    convert_row<MODE>(r + 1, lane128, emin, invd, conv, nxt, eLn, eRn);

    // horizontal neighbors of cur (converted >=1 step ago -> no wait)
    float L = __shfl_up(cur[7], 1, 64);
    float R = __shfl_down(cur[0], 1, 64);
    if (lane128 == 0)   L = 0.f;       // image left edge
    else if (wl == 0)   L = eLc;       // cross-wave
    if (lane128 == 127) R = 0.f;       // image right edge
    else if (wl == 63)  R = eRc;       // cross-wave

    // dilation = 0.2*(c + l + r + up + dn); erosion = relu(d - 0.5)
    float e[8];
    #pragma unroll
    for (int j = 0; j < 8; ++j) {
        float lf = (j == 0) ? L : cur[j - 1];
        float rf = (j == 7) ? R : cur[j + 1];
        e[j] = fmaxf(0.2f * (cur[j] + lf + rf + prev[j] + nxt[j]) - 0.5f, 0.f);
    }

    if (STORE) {
        half8_t o;
        #pragma unroll
        for (int j = 0; j < 8; ++j) o[j] = (_Float16)e[j];
        // nt: field is write-once per pass; keep it from write-allocating in
        // L2 (4 MiB/XCD) where it evicts read-reuse lines. Consecutive blocks
        // land on different XCDs, so cross-block halo reuse never L2-hits
        // anyway.
        __builtin_nontemporal_store(o, (half8_t*)(out + base + (size_t)r * W + col));
    }

    float rm = fmaxf(fmaxf(fmaxf(e[0], e[1]), fmaxf(e[2], e[3])),
                     fmaxf(fmaxf(e[4], e[5]), fmaxf(e[6], e[7])));
    float rn = fminf(fminf(fminf(e[0], e[1]), fminf(e[2], e[3])),
                     fminf(fminf(e[4], e[5]), fminf(e[6], e[7])));
    float rs = ((e[0] + e[1]) + (e[2] + e[3])) + ((e[4] + e[5]) + (e[6] + e[7]));
    m   = fmaxf(m, rm);
    mn  = fminf(mn, rn);
    sum += (double)rs;

    #pragma unroll
    for (int j = 0; j < 8; ++j) { prev[j] = cur[j]; cur[j] = nxt[j]; }
    eLc = eLn; eRc = eRn;
}

// One strip = 32 rows of one image; threads 0-127 rows [r0,r0+16),
// threads 128-255 rows [r0+16,r0+32); 8 px/thread. 3-row fp32 sliding window
// with double-buffered raw lookahead: while computing row r, row r+2's load
// is in flight and row r+1 (issued last step) is converted.
template <int MODE, int STORE>
__device__ __forceinline__ void do_strip(
    const float* __restrict__ pred, const int* __restrict__ target,
    const _Float16* __restrict__ in, _Float16* __restrict__ out,
    Stats* __restrict__ st, int iter, int strip, int tid)
{
    const int b   = strip >> 5;            // / STRIPS (=32)
    const int s   = strip & (STRIPS - 1);
    const int sub     = tid >> 7;          // 0 or 1
    const int lane128 = tid & 127;
    const int wl      = lane128 & 63;
    const int r0  = s * BROWS + sub * SROWS;
    const int col = lane128 * 8;
    const size_t base = (size_t)b * NPIX;

    float emin = 0.f, invd = 1.f;
    if (MODE == 1) {
        float emax  = __uint_as_float(st->maxbits[iter - 1][b]);
        float emn   = __uint_as_float(st->minbits[iter - 1][b]);
        float denom = emax - emn;
        if (denom != 0.f) { emin = emn; invd = 1.f / denom; }
        // else: identity -> erosion kept raw, matching reference
    }

    Raw<MODE> rA, rB;
    float prev[8], cur[8], nxt[8];
    float eLc, eRc, dL, dR;

    // Prologue: rows r0-1 (prev) and r0 (cur); then issue r0+1 into rA.
    issue_row<MODE>(pred, target, in, base, r0 - 1, lane128, rA);
    issue_row<MODE>(pred, target, in, base, r0,     lane128, rB);
    convert_row<MODE>(r0 - 1, lane128, emin, invd, rA, prev, dL, dR);
    convert_row<MODE>(r0,     lane128, emin, invd, rB, cur, eLc, eRc);
    issue_row<MODE>(pred, target, in, base, r0 + 1, lane128, rA);

    float  m  = 0.f;                 // erosion >= 0
    float  mn = __builtin_inf();
    double sum = 0.0;

    // even step: stage -> rB, convert <- rA; odd step: stage -> rA, convert <- rB
    for (int ii = 0; ii < SROWS; ii += 2) {
        strip_step<MODE, STORE>(ii,     r0, lane128, wl, col, base, pred, target, in, out,
                                emin, invd, rB, rA, prev, cur, nxt, eLc, eRc, m, mn, sum);
        strip_step<MODE, STORE>(ii + 1, r0, lane128, wl, col, base, pred, target, in, out,
                                emin, invd, rA, rB, prev, cur, nxt, eLc, eRc, m, mn, sum);
    }

    // Block reduction: max / min / sum(double), then one atomic set per block.
    #pragma unroll
    for (int off = 32; off > 0; off >>= 1) {
        m   = fmaxf(m,  __shfl_down(m,  off, 64));
        mn  = fminf(mn, __shfl_down(mn, off, 64));
        sum += __shfl_down(sum, off, 64);
    }
    __shared__ float  smax[4];
    __shared__ float  smin[4];
    __shared__ double ssum[4];
    const int lane = tid & 63, wave = tid >> 6;
    if (lane == 0) { smax[wave] = m; smin[wave] = mn; ssum[wave] = sum; }
    __syncthreads();
    if (tid == 0) {
        m   = fmaxf(fmaxf(smax[0], smax[1]), fmaxf(smax[2], smax[3]));
        mn  = fminf(fminf(smin[0], smin[1]), fminf(smin[2], smin[3]));
        sum = ssum[0] + ssum[1] + ssum[2] + ssum[3];
        atomicMax(&st->maxbits[iter][b], __float_as_uint(m));
        atomicMin(&st->minbits[iter][b], __float_as_uint(mn));
        atomicAdd(&st->sum[iter][b], sum);
    }
}

// Iteration 0: reads pred(fp32)+target(int32), 256 MB compulsory.
__global__ __launch_bounds__(256) void erode0(
    const float* __restrict__ pred, const int* __restrict__ target,
    _Float16* __restrict__ out, Stats* __restrict__ st)
{
    do_strip<0, 1>(pred, target, nullptr, out, st, 0, blockIdx.x, threadIdx.x);
}

// Iterations 1..9: fp16 field (64 MB, LLC-resident).
template <int STORE>
__global__ __launch_bounds__(256) void erode1(
    const _Float16* __restrict__ in, _Float16* __restrict__ out,
    Stats* __restrict__ st, int iter)
{
    do_strip<1, STORE>(nullptr, nullptr, in, out, st, iter, blockIdx.x, threadIdx.x);
}

// loss = (1/(B*N)) * sum_k (k+1)^2 * [ (sum_raw - N*emin)/denom  if denom != 0 else sum_raw ]
__global__ void finalize(const Stats* __restrict__ st, float* __restrict__ out) {
    if (threadIdx.x == 0 && blockIdx.x == 0) {
        double total = 0.0;
        for (int k = 0; k < ITERS; ++k) {
            double w = (double)((k + 1) * (k + 1));
            for (int b = 0; b < BATCH; ++b) {
                float emax  = __uint_as_float(st->maxbits[k][b]);
                float emn   = __uint_as_float(st->minbits[k][b]);
                float denom = emax - emn;
                double s = st->sum[k][b];
                double sn;
                if (denom != 0.f)
                    sn = (s - (double)NPIX * (double)emn) / (double)denom;
                else
                    sn = s;
                total += w * sn;
            }
        }
        out[0] = (float)(total / ((double)BATCH * (double)NPIX));
    }
}

extern "C" void kernel_launch(void* const* d_in, const int* in_sizes, int n_in,
                              void* d_out, int out_size, void* d_ws, size_t ws_size,
                              hipStream_t stream) {
    (void)in_sizes; (void)n_in; (void)out_size;
    const float* pred   = (const float*)d_in[0];
    const int*   target = (const int*)d_in[1];

    const size_t fieldBytes = (size_t)BATCH * NPIX * sizeof(_Float16);  // 64 MB
    char* ws = (char*)d_ws;
    _Float16* bufA;
    _Float16* bufB;
    Stats* st;
    if (ws_size >= 2 * fieldBytes + sizeof(Stats)) {
        bufA = (_Float16*)ws;
        bufB = (_Float16*)(ws + fieldBytes);
        st   = (Stats*)(ws + 2 * fieldBytes);
    } else {
        // target is dead after iteration 0 (128 MB int32 holds the 64 MB fp16
        // field); harness restores d_in before every launch. k=0 reads target
        // and writes bufA; bufB (=target memory) is first written at k=1.
        bufA = (_Float16*)ws;
        bufB = (_Float16*)d_in[1];
        st   = (Stats*)(ws + fieldBytes);
    }

    init_stats<<<1, 320, 0, stream>>>(st);

    dim3 grid(TOTAL_STRIPS), block(256);
    erode0<<<grid, block, 0, stream>>>(pred, target, bufA, st);

    _Float16* src = bufA;
    _Float16* dst = bufB;
    for (int k = 1; k < ITERS; ++k) {
        if (k == ITERS - 1)
            erode1<0><<<grid, block, 0, stream>>>(src, nullptr, st, k);
        else
            erode1<1><<<grid, block, 0, stream>>>(src, dst, st, k);
        _Float16* t = src; src = dst; dst = t;
    }

    finalize<<<1, 64, 0, stream>>>(st, (float*)d_out);
}